// Round 6
// baseline (181.257 us; speedup 1.0000x reference)
//
#include <hip/hip_runtime.h>

#define S    56
#define SS   3136        // 56*56
#define CD   64
#define C0   128
#define NB   16
#define EPSF 1e-5f
#define L2E  1.44269504088896f

typedef __attribute__((ext_vector_type(8))) short short8;
typedef __attribute__((ext_vector_type(4))) float f32x4;
typedef __attribute__((ext_vector_type(2))) float f32x2;
typedef unsigned short ushort_t;

__device__ __forceinline__ ushort_t f2bf(float f) {
    unsigned u = __builtin_bit_cast(unsigned, f);
    unsigned r = u + 0x7FFFu + ((u >> 16) & 1u);
    return (ushort_t)(r >> 16);
}
__device__ __forceinline__ float bf2f(ushort_t u) {
    return __builtin_bit_cast(float, (unsigned)u << 16);
}
__device__ __forceinline__ f32x2 pkfma(f32x2 a, f32x2 b, f32x2 c) {
    return __builtin_elementwise_fma(a, b, c);
}
__device__ __forceinline__ f32x2 pkmax(f32x2 a, f32x2 b) {
    return __builtin_elementwise_max(a, b);
}
__device__ __forceinline__ f32x2 splat2(float v) { return (f32x2){v, v}; }

#if __has_builtin(__builtin_amdgcn_exp2f)
#define EXP2F __builtin_amdgcn_exp2f
#else
#define EXP2F exp2f
#endif

// ---------------------------------------------------------------------------
// MFMA GEMM (conv_down / conv_up): out[o][m] = BN(sum_c w[o][c]*x[c][m])
// ---------------------------------------------------------------------------
template <int KC, int OC>
__global__ __launch_bounds__(256)
void gemm_mfma(const float* __restrict__ xin, const float* __restrict__ w,
               const float* __restrict__ bn, const float* __restrict__ resid,
               float* __restrict__ out, int relu_in, int relu_out)
{
    constexpr int KSTEPS = KC / 32;
    constexpr int OT     = OC / 64;
    __shared__ char  xT[64 * KC * 2];
    __shared__ float sS[OC], sB[OC];

    int tid = threadIdx.x;
    int n = blockIdx.x / 49, mt = blockIdx.x - (blockIdx.x / 49) * 49;
    int m0 = mt * 64;

    if (tid < OC) {
        float s = bn[tid] * rsqrtf(bn[3 * OC + tid] + EPSF);
        sS[tid] = s;
        sB[tid] = bn[OC + tid] - s * bn[2 * OC + tid];
    }

    int m_l = tid & 63, cq = tid >> 6;
    const float* xb = xin + (size_t)n * KC * SS + m0 + m_l;
    #pragma unroll
    for (int r = 0; r < KSTEPS; ++r) {
        int cbase = cq * 8 + r * 32;
        float v[8];
        #pragma unroll
        for (int u = 0; u < 8; ++u) v[u] = xb[(size_t)(cbase + u) * SS];
        if (relu_in) {
            #pragma unroll
            for (int u = 0; u < 8; ++u) v[u] = fmaxf(v[u], 0.f);
        }
        short8 sv;
        #pragma unroll
        for (int u = 0; u < 8; ++u) ((ushort_t*)&sv)[u] = f2bf(v[u]);
        *(short8*)(xT + m_l * (KC * 2) + ((cbase * 2) ^ ((m_l & 7) << 4))) = sv;
    }
    __syncthreads();

    int wave = tid >> 6, lane = tid & 63;
    int lo = lane & 15, hi = lane >> 4;

    short8 afrag[OT][KSTEPS];
    #pragma unroll
    for (int ot = 0; ot < OT; ++ot) {
        int o = (wave + ot * 4) * 16 + lo;
        #pragma unroll
        for (int ks = 0; ks < KSTEPS; ++ks) {
            const float* wr = w + (size_t)o * KC + ks * 32 + hi * 8;
            short8 a;
            #pragma unroll
            for (int u = 0; u < 8; ++u) ((ushort_t*)&a)[u] = f2bf(wr[u]);
            afrag[ot][ks] = a;
        }
    }

    f32x4 acc[OT][4];
    #pragma unroll
    for (int ot = 0; ot < OT; ++ot)
        #pragma unroll
        for (int ms = 0; ms < 4; ++ms)
            acc[ot][ms] = (f32x4){0.f, 0.f, 0.f, 0.f};

    #pragma unroll
    for (int ms = 0; ms < 4; ++ms) {
        int m_loc = ms * 16 + lo;
        #pragma unroll
        for (int ks = 0; ks < KSTEPS; ++ks) {
            short8 b = *(const short8*)(xT + m_loc * (KC * 2) +
                        (((ks * 32 + hi * 8) * 2) ^ ((m_loc & 7) << 4)));
            #pragma unroll
            for (int ot = 0; ot < OT; ++ot)
                acc[ot][ms] = __builtin_amdgcn_mfma_f32_16x16x32_bf16(
                                  afrag[ot][ks], b, acc[ot][ms], 0, 0, 0);
        }
    }

    #pragma unroll
    for (int ot = 0; ot < OT; ++ot) {
        int o_base = (wave + ot * 4) * 16;
        #pragma unroll
        for (int ms = 0; ms < 4; ++ms) {
            #pragma unroll
            for (int r = 0; r < 4; ++r) {
                int o = o_base + hi * 4 + r;
                int m = m0 + ms * 16 + lo;
                float val = acc[ot][ms][r] * sS[o] + sB[o];
                if (resid) val += resid[((size_t)n * OC + o) * SS + m];
                if (relu_out) val = fmaxf(val, 0.f);
                out[((size_t)n * OC + o) * SS + m] = val;
            }
        }
    }
}

// ---------------------------------------------------------------------------
// qkv GEMM: KC=64 -> OC=128 with BN folded.  q channels (x foldq = s_qk*log2e)
// -> qpack[n][32][m]; k/v channels -> kvpack[n*3136 + m][96] via LDS tile.
// ---------------------------------------------------------------------------
__global__ __launch_bounds__(256)
void qkv_gemm_mfma(const float* __restrict__ xin, const float* __restrict__ w,
                   const float* __restrict__ bn, const float* __restrict__ bnsim,
                   float* __restrict__ qpack, float* __restrict__ kvpack)
{
    constexpr int KC = 64, OC = 128;
    __shared__ char  xT[64 * KC * 2];
    __shared__ float sS[OC], sB[OC];
    __shared__ float kvtile[64][96];
    __shared__ float foldq[8];

    int tid = threadIdx.x;
    int n = blockIdx.x / 49, mt = blockIdx.x - (blockIdx.x / 49) * 49;
    int m0 = mt * 64;

    if (tid < OC) {
        float s = bn[tid] * rsqrtf(bn[3 * OC + tid] + EPSF);
        sS[tid] = s;
        sB[tid] = bn[OC + tid] - s * bn[2 * OC + tid];
    }
    if (tid < 8) foldq[tid] = bnsim[tid] * rsqrtf(bnsim[72 + tid] + EPSF) * L2E;

    int m_l = tid & 63, cq = tid >> 6;
    const float* xb = xin + (size_t)n * KC * SS + m0 + m_l;
    #pragma unroll
    for (int r = 0; r < 2; ++r) {
        int cbase = cq * 8 + r * 32;
        short8 sv;
        #pragma unroll
        for (int u = 0; u < 8; ++u)
            ((ushort_t*)&sv)[u] = f2bf(xb[(size_t)(cbase + u) * SS]);
        *(short8*)(xT + m_l * (KC * 2) + ((cbase * 2) ^ ((m_l & 7) << 4))) = sv;
    }
    __syncthreads();

    int wave = tid >> 6, lane = tid & 63;
    int lo = lane & 15, hi = lane >> 4;

    short8 afrag[2][2];
    #pragma unroll
    for (int ot = 0; ot < 2; ++ot) {
        int o = (wave + ot * 4) * 16 + lo;
        #pragma unroll
        for (int ks = 0; ks < 2; ++ks) {
            const float* wr = w + (size_t)o * KC + ks * 32 + hi * 8;
            short8 a;
            #pragma unroll
            for (int u = 0; u < 8; ++u) ((ushort_t*)&a)[u] = f2bf(wr[u]);
            afrag[ot][ks] = a;
        }
    }

    f32x4 acc[2][4];
    #pragma unroll
    for (int ot = 0; ot < 2; ++ot)
        #pragma unroll
        for (int ms = 0; ms < 4; ++ms)
            acc[ot][ms] = (f32x4){0.f, 0.f, 0.f, 0.f};

    #pragma unroll
    for (int ms = 0; ms < 4; ++ms) {
        int m_loc = ms * 16 + lo;
        #pragma unroll
        for (int ks = 0; ks < 2; ++ks) {
            short8 b = *(const short8*)(xT + m_loc * (KC * 2) +
                        (((ks * 32 + hi * 8) * 2) ^ ((m_loc & 7) << 4)));
            #pragma unroll
            for (int ot = 0; ot < 2; ++ot)
                acc[ot][ms] = __builtin_amdgcn_mfma_f32_16x16x32_bf16(
                                  afrag[ot][ks], b, acc[ot][ms], 0, 0, 0);
        }
    }

    #pragma unroll
    for (int ot = 0; ot < 2; ++ot) {
        int o_base = (wave + ot * 4) * 16;
        #pragma unroll
        for (int ms = 0; ms < 4; ++ms) {
            int m_loc = ms * 16 + lo;
            #pragma unroll
            for (int r = 0; r < 4; ++r) {
                int o = o_base + hi * 4 + r;
                float val = acc[ot][ms][r] * sS[o] + sB[o];
                int g = o >> 4, part = o & 15;
                if (part < 4) {
                    qpack[((size_t)n * 32 + g * 4 + part) * SS + m0 + m_loc] =
                        val * foldq[g];
                } else if (part < 8) {
                    kvtile[m_loc][(g & 3) * 8 + (part - 4) * 2 + (g >> 2)] = val;
                } else {
                    kvtile[m_loc][32 + (g & 3) * 16 + (part - 8) * 2 + (g >> 2)] = val;
                }
            }
        }
    }
    __syncthreads();
    float4* kvout = (float4*)(kvpack + ((size_t)n * SS + m0) * 96);
    const float4* kvt = (const float4*)&kvtile[0][0];
    for (int idx = tid; idx < 64 * 96 / 4; idx += 256) kvout[idx] = kvt[idx];
}

// ---------------------------------------------------------------------------
// Transpose last two 56x56 dims.
// ---------------------------------------------------------------------------
__global__ __launch_bounds__(256)
void transpose_hw(const float* __restrict__ in, float* __restrict__ out)
{
    __shared__ float t[S][S + 1];
    size_t base = (size_t)blockIdx.x * SS;
    for (int idx = threadIdx.x; idx < SS; idx += 256) {
        int a = idx / S, b = idx - (idx / S) * S;
        t[a][b] = in[base + idx];
    }
    __syncthreads();
    for (int idx = threadIdx.x; idx < SS; idx += 256) {
        int b = idx / S, a = idx - (idx / S) * S;
        out[base + idx] = t[a][b];
    }
}

// ---------------------------------------------------------------------------
// Attention core v4: flash-style j-split across wave halves.
// Block = 512 threads = 8 waves.  wave -> (pair = wv&3, half = wv>>2).
// pair handles groups (pair, pair+4) packed as f32x2; half handles
// j in [half*28, half*28+28).  Partials merged via LDS.
// ---------------------------------------------------------------------------
__global__ __launch_bounds__(512)
void attn_core(const float* __restrict__ qpack,
               const float* __restrict__ kvpack,
               const float* __restrict__ bnsim,  // 4 x 24
               const float* __restrict__ bnout,  // 4 x 128
               const float* __restrict__ rel,    // 16 x 111
               float* __restrict__ xout)
{
    __shared__ float    sqp[64][34];     // [l][pair-col]; rows >=56 zero
    __shared__ ushort_t rqk[120][8];     // {qemb[c][d], kemb[c][110-d]}
    __shared__ ushort_t rvv[120][8];     // {vemb[c][d]}
    __shared__ float    comb[4][64][38]; // [pair][lane][{m2,Z2,av2[8],ae2[8]}]

    int tid = threadIdx.x;
    int n = blockIdx.x / S, p = blockIdx.x - (blockIdx.x / S) * S;

    for (int idx = tid; idx < 64 * 34; idx += 512) ((float*)sqp)[idx] = 0.f;
    for (int idx = tid; idx < 120 * 8 / 2; idx += 512) {
        ((unsigned*)rqk)[idx] = 0u;
        ((unsigned*)rvv)[idx] = 0u;
    }
    __syncthreads();

    const float* qb = qpack + (size_t)n * 32 * SS + (size_t)p * S;
    for (int idx = tid; idx < 32 * S; idx += 512) {
        int qc = idx / S, l = idx - (idx / S) * S;
        int g = qc >> 2, c = qc & 3;
        sqp[l][((g & 3) * 4 + c) * 2 + (g >> 2)] = qb[(size_t)qc * SS + l];
    }
    for (int idx = tid; idx < 16 * 111; idx += 512) {
        int c = idx / 111, d = idx - (idx / 111) * 111;
        float v = rel[idx];
        if (c < 4)      rqk[d][c] = f2bf(v);
        else if (c < 8) rqk[110 - d][c] = f2bf(v);
        else            rvv[d][c - 8] = f2bf(v);
    }
    __syncthreads();

    const int wvid = __builtin_amdgcn_readfirstlane(tid >> 6);
    const int pair = wvid & 3, half = wvid >> 2;
    const int i  = tid & 63;
    const int g0 = pair, g1 = pair + 4;

    float sqk0 = bnsim[g0] * rsqrtf(bnsim[72 + g0] + EPSF);
    float sqr0 = bnsim[8 + g0] * rsqrtf(bnsim[80 + g0] + EPSF);
    float skr0 = bnsim[16 + g0] * rsqrtf(bnsim[88 + g0] + EPSF);
    float bsm0 = (bnsim[24 + g0] - sqk0 * bnsim[48 + g0])
               + (bnsim[32 + g0] - sqr0 * bnsim[56 + g0])
               + (bnsim[40 + g0] - skr0 * bnsim[64 + g0]);
    float sqk1 = bnsim[g1] * rsqrtf(bnsim[72 + g1] + EPSF);
    float sqr1 = bnsim[8 + g1] * rsqrtf(bnsim[80 + g1] + EPSF);
    float skr1 = bnsim[16 + g1] * rsqrtf(bnsim[88 + g1] + EPSF);
    float bsm1 = (bnsim[24 + g1] - sqk1 * bnsim[48 + g1])
               + (bnsim[32 + g1] - sqr1 * bnsim[56 + g1])
               + (bnsim[40 + g1] - skr1 * bnsim[64 + g1]);
    f32x2 cqr2 = {sqr0 / sqk0, sqr1 / sqk1};
    f32x2 ckr2 = {skr0 * L2E,  skr1 * L2E};
    f32x2 bs2  = {bsm0 * L2E,  bsm1 * L2E};

    f32x2 q2[4];
    #pragma unroll
    for (int c = 0; c < 4; ++c)
        q2[c] = *(const f32x2*)&sqp[i][(pair * 4 + c) * 2];

    const float* kvb = kvpack + ((size_t)n * SS + (size_t)p * S) * 96;

    f32x2 mr2 = splat2(-3e38f), Z2 = splat2(0.f);
    f32x2 av2[8], ae2[8];
    #pragma unroll
    for (int c = 0; c < 8; ++c) { av2[c] = splat2(0.f); ae2[c] = splat2(0.f); }

    const int jbeg = half * 28;
    for (int cc = 0; cc < 4; ++cc) {
        const int j0 = jbeg + cc * 7;
        const float* krow = kvb + j0 * 96 + pair * 8;
        f32x2 pc2[7];
        #pragma unroll
        for (int u = 0; u < 7; ++u) {
            const float* kj = krow + u * 96;
            short8 rr = *(const short8*)&rqk[i - (j0 + u) + 55][0];
            f32x2 qk2 = splat2(0.f), qr2 = splat2(0.f), kr2 = splat2(0.f);
            #pragma unroll
            for (int c = 0; c < 4; ++c) {
                f32x2 k2 = *(const f32x2*)(kj + c * 2);
                qk2 = pkfma(q2[c], k2, qk2);
                qr2 = pkfma(q2[c], splat2(bf2f(((const ushort_t*)&rr)[c])), qr2);
                kr2 = pkfma(k2,    splat2(bf2f(((const ushort_t*)&rr)[4 + c])), kr2);
            }
            pc2[u] = qk2 + pkfma(cqr2, qr2, pkfma(ckr2, kr2, bs2));
        }
        f32x2 cm2 = pc2[0];
        #pragma unroll
        for (int u = 1; u < 7; ++u) cm2 = pkmax(cm2, pc2[u]);
        f32x2 nm2 = pkmax(mr2, cm2);
        float dm = fmaxf(nm2.x - mr2.x, nm2.y - mr2.y);
        if (!__all(dm <= 12.0f)) {
            f32x2 sc2;
            sc2.x = EXP2F(mr2.x - nm2.x);
            sc2.y = EXP2F(mr2.y - nm2.y);
            mr2 = nm2;
            Z2 *= sc2;
            #pragma unroll
            for (int c = 0; c < 8; ++c) { av2[c] *= sc2; ae2[c] *= sc2; }
        }
        const float* vrow = kvb + j0 * 96 + 32 + pair * 16;
        #pragma unroll
        for (int u = 0; u < 7; ++u) {
            f32x2 e2;
            e2.x = EXP2F(pc2[u].x - mr2.x);
            e2.y = EXP2F(pc2[u].y - mr2.y);
            Z2 += e2;
            const float* vj = vrow + u * 96;
            short8 rv = *(const short8*)&rvv[i - (j0 + u) + 55][0];
            #pragma unroll
            for (int c = 0; c < 8; ++c) {
                av2[c] = pkfma(e2, *(const f32x2*)(vj + c * 2), av2[c]);
                ae2[c] = pkfma(e2, splat2(bf2f(((const ushort_t*)&rv)[c])), ae2[c]);
            }
        }
    }

    // merge the two j-halves through LDS
    if (half == 1) {
        f32x2* dst = (f32x2*)&comb[pair][i][0];
        dst[0] = mr2; dst[1] = Z2;
        #pragma unroll
        for (int c = 0; c < 8; ++c) { dst[2 + c] = av2[c]; dst[10 + c] = ae2[c]; }
    }
    __syncthreads();
    if (half == 0 && i < S) {
        const f32x2* src = (const f32x2*)&comb[pair][i][0];
        f32x2 m1 = src[0], Z1 = src[1];
        f32x2 nm = pkmax(mr2, m1);
        f32x2 s0, s1;
        s0.x = EXP2F(mr2.x - nm.x); s0.y = EXP2F(mr2.y - nm.y);
        s1.x = EXP2F(m1.x - nm.x);  s1.y = EXP2F(m1.y - nm.y);
        f32x2 Z = Z2 * s0 + Z1 * s1;
        f32x2 inv2 = {1.f / Z.x, 1.f / Z.y};
        size_t ob = (size_t)n * (CD * SS) + (size_t)p * S + i;
        #pragma unroll
        for (int c = 0; c < 8; ++c) {
            f32x2 av = av2[c] * s0 + src[2 + c] * s1;
            f32x2 ae = ae2[c] * s0 + src[10 + c] * s1;
            int ch0 = pair * 8 + c, ch1 = ch0 + 32;
            int oa = ch0 * 2, obq = ch1 * 2;
            float se0 = bnout[oa] * rsqrtf(bnout[384 + oa] + EPSF);
            float be0 = bnout[128 + oa] - se0 * bnout[256 + oa];
            float so0 = bnout[oa + 1] * rsqrtf(bnout[384 + oa + 1] + EPSF);
            float bo0 = bnout[128 + oa + 1] - so0 * bnout[256 + oa + 1];
            float se1 = bnout[obq] * rsqrtf(bnout[384 + obq] + EPSF);
            float be1 = bnout[128 + obq] - se1 * bnout[256 + obq];
            float so1 = bnout[obq + 1] * rsqrtf(bnout[384 + obq + 1] + EPSF);
            float bo1 = bnout[128 + obq + 1] - so1 * bnout[256 + obq + 1];
            xout[ob + (size_t)ch0 * SS] =
                inv2.x * (se0 * av.x + so0 * ae.x) + (be0 + bo0);
            xout[ob + (size_t)ch1 * SS] =
                inv2.y * (se1 * av.y + so1 * ae.y) + (be1 + bo1);
        }
    }
}

extern "C" void kernel_launch(void* const* d_in, const int* in_sizes, int n_in,
                              void* d_out, int out_size, void* d_ws, size_t ws_size,
                              hipStream_t stream)
{
    const float* x      = (const float*)d_in[0];
    const float* cdw    = (const float*)d_in[1];
    const float* bn1    = (const float*)d_in[2];
    const float* hqkv   = (const float*)d_in[3];
    const float* hbnqkv = (const float*)d_in[4];
    const float* hbnsim = (const float*)d_in[5];
    const float* hbnout = (const float*)d_in[6];
    const float* hrel   = (const float*)d_in[7];
    const float* wqkv   = (const float*)d_in[8];
    const float* wbnqkv = (const float*)d_in[9];
    const float* wbnsim = (const float*)d_in[10];
    const float* wbnout = (const float*)d_in[11];
    const float* wrel   = (const float*)d_in[12];
    const float* cuw    = (const float*)d_in[13];
    const float* bn2    = (const float*)d_in[14];

    float* bufA   = (float*)d_ws;                        // 16*64*3136
    float* bufB   = bufA + (size_t)NB * CD * SS;         // 16*64*3136
    float* qpack  = bufB + (size_t)NB * CD * SS;         // 16*32*3136
    float* kvpack = qpack + (size_t)NB * 32 * SS;        // 16*3136*96

    // 1. conv_down + BN + ReLU -> bufA [b,c,(h,w)]
    gemm_mfma<128, 64><<<NB * 49, 256, 0, stream>>>(x, cdw, bn1, nullptr, bufA, 0, 1);
    // 2. transpose -> bufB [b,c,(w,h)]
    transpose_hw<<<NB * CD, 256, 0, stream>>>(bufA, bufB);
    // 3. qkv GEMM (H) -> qpack, kvpack
    qkv_gemm_mfma<<<NB * 49, 256, 0, stream>>>(bufB, hqkv, hbnqkv, hbnsim, qpack, kvpack);
    // 4. attn H: p=w, i=h -> bufA [b,c,w,h]
    attn_core<<<NB * S, 512, 0, stream>>>(qpack, kvpack, hbnsim, hbnout, hrel, bufA);
    // 5. transpose -> bufB [b,c,(h,w)]
    transpose_hw<<<NB * CD, 256, 0, stream>>>(bufA, bufB);
    // 6. qkv GEMM (W) -> qpack, kvpack
    qkv_gemm_mfma<<<NB * 49, 256, 0, stream>>>(bufB, wqkv, wbnqkv, wbnsim, qpack, kvpack);
    // 7. attn W: p=h, i=w -> bufA [b,c,h,w]
    attn_core<<<NB * S, 512, 0, stream>>>(qpack, kvpack, wbnsim, wbnout, wrel, bufA);
    // 8. ReLU-in + conv_up + BN + resid + ReLU -> d_out
    gemm_mfma<64, 128><<<NB * 49, 256, 0, stream>>>(bufA, cuw, bn2, x, (float*)d_out, 1, 1);
}

// Round 7
// 157.713 us; speedup vs baseline: 1.1493x; 1.1493x over previous
//
#include <hip/hip_runtime.h>

#define S    56
#define SS   3136        // 56*56
#define CD   64
#define C0   128
#define NB   16
#define EPSF 1e-5f
#define L2E  1.44269504088896f

typedef __attribute__((ext_vector_type(8))) short short8;
typedef __attribute__((ext_vector_type(4))) float f32x4;
typedef __attribute__((ext_vector_type(2))) float f32x2;
typedef unsigned short ushort_t;

__device__ __forceinline__ ushort_t f2bf(float f) {
    unsigned u = __builtin_bit_cast(unsigned, f);
    unsigned r = u + 0x7FFFu + ((u >> 16) & 1u);
    return (ushort_t)(r >> 16);
}
__device__ __forceinline__ float lo2f(unsigned w) {
    return __builtin_bit_cast(float, w << 16);
}
__device__ __forceinline__ float hi2f(unsigned w) {
    return __builtin_bit_cast(float, w & 0xffff0000u);
}
__device__ __forceinline__ f32x2 pkfma(f32x2 a, f32x2 b, f32x2 c) {
    return __builtin_elementwise_fma(a, b, c);
}
__device__ __forceinline__ f32x2 pkmax(f32x2 a, f32x2 b) {
    return __builtin_elementwise_max(a, b);
}
__device__ __forceinline__ f32x2 splat2(float v) { return (f32x2){v, v}; }

#if __has_builtin(__builtin_amdgcn_exp2f)
#define EXP2F __builtin_amdgcn_exp2f
#else
#define EXP2F exp2f
#endif

// ---------------------------------------------------------------------------
// MFMA GEMM (conv_down / conv_up): out[o][m] = BN(sum_c w[o][c]*x[c][m])
// ---------------------------------------------------------------------------
template <int KC, int OC>
__global__ __launch_bounds__(256)
void gemm_mfma(const float* __restrict__ xin, const float* __restrict__ w,
               const float* __restrict__ bn, const float* __restrict__ resid,
               float* __restrict__ out, int relu_in, int relu_out)
{
    constexpr int KSTEPS = KC / 32;
    constexpr int OT     = OC / 64;
    __shared__ char  xT[64 * KC * 2];
    __shared__ float sS[OC], sB[OC];

    int tid = threadIdx.x;
    int n = blockIdx.x / 49, mt = blockIdx.x - (blockIdx.x / 49) * 49;
    int m0 = mt * 64;

    if (tid < OC) {
        float s = bn[tid] * rsqrtf(bn[3 * OC + tid] + EPSF);
        sS[tid] = s;
        sB[tid] = bn[OC + tid] - s * bn[2 * OC + tid];
    }

    int m_l = tid & 63, cq = tid >> 6;
    const float* xb = xin + (size_t)n * KC * SS + m0 + m_l;
    #pragma unroll
    for (int r = 0; r < KSTEPS; ++r) {
        int cbase = cq * 8 + r * 32;
        float v[8];
        #pragma unroll
        for (int u = 0; u < 8; ++u) v[u] = xb[(size_t)(cbase + u) * SS];
        if (relu_in) {
            #pragma unroll
            for (int u = 0; u < 8; ++u) v[u] = fmaxf(v[u], 0.f);
        }
        short8 sv;
        #pragma unroll
        for (int u = 0; u < 8; ++u) ((ushort_t*)&sv)[u] = f2bf(v[u]);
        *(short8*)(xT + m_l * (KC * 2) + ((cbase * 2) ^ ((m_l & 7) << 4))) = sv;
    }
    __syncthreads();

    int wave = tid >> 6, lane = tid & 63;
    int lo = lane & 15, hi = lane >> 4;

    short8 afrag[OT][KSTEPS];
    #pragma unroll
    for (int ot = 0; ot < OT; ++ot) {
        int o = (wave + ot * 4) * 16 + lo;
        #pragma unroll
        for (int ks = 0; ks < KSTEPS; ++ks) {
            const float* wr = w + (size_t)o * KC + ks * 32 + hi * 8;
            short8 a;
            #pragma unroll
            for (int u = 0; u < 8; ++u) ((ushort_t*)&a)[u] = f2bf(wr[u]);
            afrag[ot][ks] = a;
        }
    }

    f32x4 acc[OT][4];
    #pragma unroll
    for (int ot = 0; ot < OT; ++ot)
        #pragma unroll
        for (int ms = 0; ms < 4; ++ms)
            acc[ot][ms] = (f32x4){0.f, 0.f, 0.f, 0.f};

    #pragma unroll
    for (int ms = 0; ms < 4; ++ms) {
        int m_loc = ms * 16 + lo;
        #pragma unroll
        for (int ks = 0; ks < KSTEPS; ++ks) {
            short8 b = *(const short8*)(xT + m_loc * (KC * 2) +
                        (((ks * 32 + hi * 8) * 2) ^ ((m_loc & 7) << 4)));
            #pragma unroll
            for (int ot = 0; ot < OT; ++ot)
                acc[ot][ms] = __builtin_amdgcn_mfma_f32_16x16x32_bf16(
                                  afrag[ot][ks], b, acc[ot][ms], 0, 0, 0);
        }
    }

    #pragma unroll
    for (int ot = 0; ot < OT; ++ot) {
        int o_base = (wave + ot * 4) * 16;
        #pragma unroll
        for (int ms = 0; ms < 4; ++ms) {
            #pragma unroll
            for (int r = 0; r < 4; ++r) {
                int o = o_base + hi * 4 + r;
                int m = m0 + ms * 16 + lo;
                float val = acc[ot][ms][r] * sS[o] + sB[o];
                if (resid) val += resid[((size_t)n * OC + o) * SS + m];
                if (relu_out) val = fmaxf(val, 0.f);
                out[((size_t)n * OC + o) * SS + m] = val;
            }
        }
    }
}

// ---------------------------------------------------------------------------
// qkv GEMM: KC=64 -> OC=128 with BN folded.  q channels (x foldq = s_qk*log2e)
// -> qpack[n][32][m]; k channels bf16 + v channels f32 -> kvpack rows of
// 80 floats: [0..15] = 32 bf16 k-slots, [16..79] = 64 f32 v-slots.
//   k slot (ushort idx) = (g&3)*8  + c*2 + (g>>2)   (c = part-4, 0..3)
//   v slot (float  idx) = (g&3)*16 + c*2 + (g>>2)   (c = part-8, 0..7)
// ---------------------------------------------------------------------------
__global__ __launch_bounds__(256)
void qkv_gemm_mfma(const float* __restrict__ xin, const float* __restrict__ w,
                   const float* __restrict__ bn, const float* __restrict__ bnsim,
                   float* __restrict__ qpack, float* __restrict__ kvpack)
{
    constexpr int KC = 64, OC = 128;
    __shared__ char  xT[64 * KC * 2];
    __shared__ float sS[OC], sB[OC];
    __shared__ ushort_t ktile[64][32];
    __shared__ float    vtile[64][64];
    __shared__ float foldq[8];

    int tid = threadIdx.x;
    int n = blockIdx.x / 49, mt = blockIdx.x - (blockIdx.x / 49) * 49;
    int m0 = mt * 64;

    if (tid < OC) {
        float s = bn[tid] * rsqrtf(bn[3 * OC + tid] + EPSF);
        sS[tid] = s;
        sB[tid] = bn[OC + tid] - s * bn[2 * OC + tid];
    }
    if (tid < 8) foldq[tid] = bnsim[tid] * rsqrtf(bnsim[72 + tid] + EPSF) * L2E;

    int m_l = tid & 63, cq = tid >> 6;
    const float* xb = xin + (size_t)n * KC * SS + m0 + m_l;
    #pragma unroll
    for (int r = 0; r < 2; ++r) {
        int cbase = cq * 8 + r * 32;
        short8 sv;
        #pragma unroll
        for (int u = 0; u < 8; ++u)
            ((ushort_t*)&sv)[u] = f2bf(xb[(size_t)(cbase + u) * SS]);
        *(short8*)(xT + m_l * (KC * 2) + ((cbase * 2) ^ ((m_l & 7) << 4))) = sv;
    }
    __syncthreads();

    int wave = tid >> 6, lane = tid & 63;
    int lo = lane & 15, hi = lane >> 4;

    short8 afrag[2][2];
    #pragma unroll
    for (int ot = 0; ot < 2; ++ot) {
        int o = (wave + ot * 4) * 16 + lo;
        #pragma unroll
        for (int ks = 0; ks < 2; ++ks) {
            const float* wr = w + (size_t)o * KC + ks * 32 + hi * 8;
            short8 a;
            #pragma unroll
            for (int u = 0; u < 8; ++u) ((ushort_t*)&a)[u] = f2bf(wr[u]);
            afrag[ot][ks] = a;
        }
    }

    f32x4 acc[2][4];
    #pragma unroll
    for (int ot = 0; ot < 2; ++ot)
        #pragma unroll
        for (int ms = 0; ms < 4; ++ms)
            acc[ot][ms] = (f32x4){0.f, 0.f, 0.f, 0.f};

    #pragma unroll
    for (int ms = 0; ms < 4; ++ms) {
        int m_loc = ms * 16 + lo;
        #pragma unroll
        for (int ks = 0; ks < 2; ++ks) {
            short8 b = *(const short8*)(xT + m_loc * (KC * 2) +
                        (((ks * 32 + hi * 8) * 2) ^ ((m_loc & 7) << 4)));
            #pragma unroll
            for (int ot = 0; ot < 2; ++ot)
                acc[ot][ms] = __builtin_amdgcn_mfma_f32_16x16x32_bf16(
                                  afrag[ot][ks], b, acc[ot][ms], 0, 0, 0);
        }
    }

    #pragma unroll
    for (int ot = 0; ot < 2; ++ot) {
        int o_base = (wave + ot * 4) * 16;
        #pragma unroll
        for (int ms = 0; ms < 4; ++ms) {
            int m_loc = ms * 16 + lo;
            #pragma unroll
            for (int r = 0; r < 4; ++r) {
                int o = o_base + hi * 4 + r;
                float val = acc[ot][ms][r] * sS[o] + sB[o];
                int g = o >> 4, part = o & 15;
                if (part < 4) {
                    qpack[((size_t)n * 32 + g * 4 + part) * SS + m0 + m_loc] =
                        val * foldq[g];
                } else if (part < 8) {
                    ktile[m_loc][(g & 3) * 8 + (part - 4) * 2 + (g >> 2)] = f2bf(val);
                } else {
                    vtile[m_loc][(g & 3) * 16 + (part - 8) * 2 + (g >> 2)] = val;
                }
            }
        }
    }
    __syncthreads();
    float4* kvout = (float4*)(kvpack + ((size_t)n * SS + m0) * 80);
    for (int idx = tid; idx < 64 * 20; idx += 256) {
        int r = idx / 20, q = idx - (idx / 20) * 20;
        float4 v;
        if (q < 4) v = *(const float4*)((const char*)&ktile[r][0] + q * 16);
        else       v = *(const float4*)&vtile[r][(q - 4) * 4];
        kvout[idx] = v;
    }
}

// ---------------------------------------------------------------------------
// Transpose last two 56x56 dims (float4 global accesses).
// ---------------------------------------------------------------------------
__global__ __launch_bounds__(256)
void transpose_hw(const float* __restrict__ in, float* __restrict__ out)
{
    __shared__ float t[S][57];
    size_t base = (size_t)blockIdx.x * SS;
    for (int idx = threadIdx.x; idx < 784; idx += 256) {
        int a = idx / 14, bq = idx - (idx / 14) * 14;
        float4 v = *(const float4*)&in[base + a * 56 + bq * 4];
        t[a][bq * 4 + 0] = v.x; t[a][bq * 4 + 1] = v.y;
        t[a][bq * 4 + 2] = v.z; t[a][bq * 4 + 3] = v.w;
    }
    __syncthreads();
    for (int idx = threadIdx.x; idx < 784; idx += 256) {
        int b = idx / 14, aq = idx - (idx / 14) * 14;
        float4 r;
        r.x = t[aq * 4 + 0][b]; r.y = t[aq * 4 + 1][b];
        r.z = t[aq * 4 + 2][b]; r.w = t[aq * 4 + 3][b];
        *(float4*)&out[base + b * 56 + aq * 4] = r;
    }
}

// ---------------------------------------------------------------------------
// Attention core v5: all inner-loop memory through LDS (in-order lgkm).
// Block = 512 threads = 8 waves; wave -> (pair = wv&3, half = wv>>2).
// pair handles groups (pair, pair+4) as f32x2; half handles 28 j's.
// K bf16-packed (1 b128/j), V f32 pair-interleaved (4 b128/j),
// rel bf16 per-lane stride-16B (2 b128/j).  Merge buffer aliases the
// staging region (dead after the j-loop).
// ---------------------------------------------------------------------------
__global__ __launch_bounds__(512)
void attn_core(const float* __restrict__ qpack,
               const float* __restrict__ kvpack,
               const float* __restrict__ bnsim,  // 4 x 24
               const float* __restrict__ bnout,  // 4 x 128
               const float* __restrict__ rel,    // 16 x 111
               float* __restrict__ xout)
{
    __shared__ __align__(16) ushort_t rqk[112][8];  // {qemb[c][d], kemb[c][110-d]}
    __shared__ __align__(16) ushort_t rvv[112][8];  // {vemb[c][d]}
    __shared__ __align__(16) float smem[4 * 64 * 38]; // union: staging | comb
    // staging: u32 kl[56][16]   = words  [0    .. 896)
    //          f32 vl[56][64]   = floats [896  .. 4480)
    //          f32 sqp[56][34]  = floats [4480 .. 6384)
    // comb:    f32 [4][64][38]  (38912 B total)

    int tid = threadIdx.x;
    int n = blockIdx.x / S, p = blockIdx.x - (blockIdx.x / S) * S;

    // stage rel (bf16, kemb reversed)
    for (int idx = tid; idx < 16 * 111; idx += 512) {
        int c = idx / 111, d = idx - (idx / 111) * 111;
        float v = rel[idx];
        if (c < 4)      rqk[d][c] = f2bf(v);
        else if (c < 8) rqk[110 - d][c] = f2bf(v);
        else            rvv[d][c - 8] = f2bf(v);
    }
    // stage q (pre-scaled by s_qk*log2e)
    float* sqp = smem + 4480;
    const float* qb = qpack + (size_t)n * 32 * SS + (size_t)p * S;
    for (int idx = tid; idx < 32 * S; idx += 512) {
        int qc = idx / S, l = idx - (idx / S) * S;
        int g = qc >> 2, c = qc & 3;
        sqp[l * 34 + ((g & 3) * 4 + c) * 2 + (g >> 2)] = qb[(size_t)qc * SS + l];
    }
    // stage K/V rows (contiguous 56*80 floats)
    const float4* kvb4 = (const float4*)(kvpack + ((size_t)n * SS + (size_t)p * S) * 80);
    for (int idx = tid; idx < 56 * 20; idx += 512) {
        int r = idx / 20, q = idx - (idx / 20) * 20;
        float4 v = kvb4[idx];
        if (q < 4) *(float4*)&smem[r * 16 + q * 4] = v;
        else       *(float4*)&smem[896 + r * 64 + (q - 4) * 4] = v;
    }
    __syncthreads();

    const int wvid = __builtin_amdgcn_readfirstlane(tid >> 6);
    const int pair = wvid & 3, half = wvid >> 2;
    const int i  = tid & 63;
    const int ic = i < S ? i : S - 1;     // lanes 56-63 mirror row 55
    const int g0 = pair, g1 = pair + 4;

    float sqk0 = bnsim[g0] * rsqrtf(bnsim[72 + g0] + EPSF);
    float sqr0 = bnsim[8 + g0] * rsqrtf(bnsim[80 + g0] + EPSF);
    float skr0 = bnsim[16 + g0] * rsqrtf(bnsim[88 + g0] + EPSF);
    float bsm0 = (bnsim[24 + g0] - sqk0 * bnsim[48 + g0])
               + (bnsim[32 + g0] - sqr0 * bnsim[56 + g0])
               + (bnsim[40 + g0] - skr0 * bnsim[64 + g0]);
    float sqk1 = bnsim[g1] * rsqrtf(bnsim[72 + g1] + EPSF);
    float sqr1 = bnsim[8 + g1] * rsqrtf(bnsim[80 + g1] + EPSF);
    float skr1 = bnsim[16 + g1] * rsqrtf(bnsim[88 + g1] + EPSF);
    float bsm1 = (bnsim[24 + g1] - sqk1 * bnsim[48 + g1])
               + (bnsim[32 + g1] - sqr1 * bnsim[56 + g1])
               + (bnsim[40 + g1] - skr1 * bnsim[64 + g1]);
    f32x2 cqr2 = {sqr0 / sqk0, sqr1 / sqk1};
    f32x2 ckr2 = {skr0 * L2E,  skr1 * L2E};
    f32x2 bs2  = {bsm0 * L2E,  bsm1 * L2E};

    f32x2 q2[4];
    #pragma unroll
    for (int c = 0; c < 4; ++c)
        q2[c] = *(const f32x2*)&sqp[ic * 34 + (pair * 4 + c) * 2];

    const unsigned* klw = (const unsigned*)smem;   // [j][16] words
    const float*    vlf = smem + 896;              // [j][64]

    f32x2 mr2 = splat2(-3e38f), Z2 = splat2(0.f);
    f32x2 av2[8], ae2[8];
    #pragma unroll
    for (int c = 0; c < 8; ++c) { av2[c] = splat2(0.f); ae2[c] = splat2(0.f); }

    const int jbeg = half * 28;
    for (int cc = 0; cc < 4; ++cc) {
        const int j0 = jbeg + cc * 7;
        f32x2 pc2[7];
        #pragma unroll
        for (int u = 0; u < 7; ++u) {
            int j = j0 + u;
            uint4 kw = *(const uint4*)&klw[j * 16 + pair * 4];
            uint4 rw = *(const uint4*)&rqk[ic - j + 55][0];
            f32x2 qk2 = splat2(0.f), qr2 = splat2(0.f), kr2 = splat2(0.f);
            #pragma unroll
            for (int c = 0; c < 4; ++c) {
                unsigned kword = ((const unsigned*)&kw)[c];
                f32x2 k2 = { lo2f(kword), hi2f(kword) };
                unsigned qw = ((const unsigned*)&rw)[c >> 1];
                unsigned ew = ((const unsigned*)&rw)[2 + (c >> 1)];
                float qe = (c & 1) ? hi2f(qw) : lo2f(qw);
                float ke = (c & 1) ? hi2f(ew) : lo2f(ew);
                qk2 = pkfma(q2[c], k2, qk2);
                qr2 = pkfma(q2[c], splat2(qe), qr2);
                kr2 = pkfma(k2, splat2(ke), kr2);
            }
            pc2[u] = qk2 + pkfma(cqr2, qr2, pkfma(ckr2, kr2, bs2));
        }
        f32x2 cm2 = pc2[0];
        #pragma unroll
        for (int u = 1; u < 7; ++u) cm2 = pkmax(cm2, pc2[u]);
        f32x2 nm2 = pkmax(mr2, cm2);
        float dm = fmaxf(nm2.x - mr2.x, nm2.y - mr2.y);
        if (!__all(dm <= 12.0f)) {
            f32x2 sc2;
            sc2.x = EXP2F(mr2.x - nm2.x);
            sc2.y = EXP2F(mr2.y - nm2.y);
            mr2 = nm2;
            Z2 *= sc2;
            #pragma unroll
            for (int c = 0; c < 8; ++c) { av2[c] *= sc2; ae2[c] *= sc2; }
        }
        #pragma unroll
        for (int u = 0; u < 7; ++u) {
            int j = j0 + u;
            f32x2 e2;
            e2.x = EXP2F(pc2[u].x - mr2.x);
            e2.y = EXP2F(pc2[u].y - mr2.y);
            Z2 += e2;
            const float* vj = vlf + j * 64 + pair * 16;
            float4 va = *(const float4*)(vj);
            float4 vb = *(const float4*)(vj + 4);
            float4 vc = *(const float4*)(vj + 8);
            float4 vd = *(const float4*)(vj + 12);
            uint4 vw = *(const uint4*)&rvv[ic - j + 55][0];
            f32x2 vv[8] = { {va.x, va.y}, {va.z, va.w}, {vb.x, vb.y}, {vb.z, vb.w},
                            {vc.x, vc.y}, {vc.z, vc.w}, {vd.x, vd.y}, {vd.z, vd.w} };
            #pragma unroll
            for (int c2 = 0; c2 < 8; ++c2) {
                unsigned w2 = ((const unsigned*)&vw)[c2 >> 1];
                float rv = (c2 & 1) ? hi2f(w2) : lo2f(w2);
                av2[c2] = pkfma(e2, vv[c2], av2[c2]);
                ae2[c2] = pkfma(e2, splat2(rv), ae2[c2]);
            }
        }
    }

    __syncthreads();                  // staging region dead everywhere
    float* comb = smem;               // [pair][64][38]
    if (half == 1) {
        float* dst = comb + ((size_t)pair * 64 + i) * 38;
        f32x2* d2 = (f32x2*)dst;
        d2[0] = mr2; d2[1] = Z2;
        #pragma unroll
        for (int c = 0; c < 8; ++c) { d2[2 + c] = av2[c]; d2[10 + c] = ae2[c]; }
    }
    __syncthreads();
    if (half == 0 && i < S) {
        const f32x2* src = (const f32x2*)(comb + ((size_t)pair * 64 + i) * 38);
        f32x2 m1 = src[0], Z1 = src[1];
        f32x2 nm = pkmax(mr2, m1);
        f32x2 s0, s1;
        s0.x = EXP2F(mr2.x - nm.x); s0.y = EXP2F(mr2.y - nm.y);
        s1.x = EXP2F(m1.x - nm.x);  s1.y = EXP2F(m1.y - nm.y);
        f32x2 Z = Z2 * s0 + Z1 * s1;
        f32x2 inv2 = {1.f / Z.x, 1.f / Z.y};
        size_t ob = (size_t)n * (CD * SS) + (size_t)p * S + i;
        #pragma unroll
        for (int c = 0; c < 8; ++c) {
            f32x2 av = av2[c] * s0 + src[2 + c] * s1;
            f32x2 ae = ae2[c] * s0 + src[10 + c] * s1;
            int ch0 = pair * 8 + c, ch1 = ch0 + 32;
            int oa = ch0 * 2, obq = ch1 * 2;
            float se0 = bnout[oa] * rsqrtf(bnout[384 + oa] + EPSF);
            float be0 = bnout[128 + oa] - se0 * bnout[256 + oa];
            float so0 = bnout[oa + 1] * rsqrtf(bnout[384 + oa + 1] + EPSF);
            float bo0 = bnout[128 + oa + 1] - so0 * bnout[256 + oa + 1];
            float se1 = bnout[obq] * rsqrtf(bnout[384 + obq] + EPSF);
            float be1 = bnout[128 + obq] - se1 * bnout[256 + obq];
            float so1 = bnout[obq + 1] * rsqrtf(bnout[384 + obq + 1] + EPSF);
            float bo1 = bnout[128 + obq + 1] - so1 * bnout[256 + obq + 1];
            xout[ob + (size_t)ch0 * SS] =
                inv2.x * (se0 * av.x + so0 * ae.x) + (be0 + bo0);
            xout[ob + (size_t)ch1 * SS] =
                inv2.y * (se1 * av.y + so1 * ae.y) + (be1 + bo1);
        }
    }
}

extern "C" void kernel_launch(void* const* d_in, const int* in_sizes, int n_in,
                              void* d_out, int out_size, void* d_ws, size_t ws_size,
                              hipStream_t stream)
{
    const float* x      = (const float*)d_in[0];
    const float* cdw    = (const float*)d_in[1];
    const float* bn1    = (const float*)d_in[2];
    const float* hqkv   = (const float*)d_in[3];
    const float* hbnqkv = (const float*)d_in[4];
    const float* hbnsim = (const float*)d_in[5];
    const float* hbnout = (const float*)d_in[6];
    const float* hrel   = (const float*)d_in[7];
    const float* wqkv   = (const float*)d_in[8];
    const float* wbnqkv = (const float*)d_in[9];
    const float* wbnsim = (const float*)d_in[10];
    const float* wbnout = (const float*)d_in[11];
    const float* wrel   = (const float*)d_in[12];
    const float* cuw    = (const float*)d_in[13];
    const float* bn2    = (const float*)d_in[14];

    float* bufA   = (float*)d_ws;                        // 16*64*3136
    float* bufB   = bufA + (size_t)NB * CD * SS;         // 16*64*3136
    float* qpack  = bufB + (size_t)NB * CD * SS;         // 16*32*3136
    float* kvpack = qpack + (size_t)NB * 32 * SS;        // 16*3136*80

    // 1. conv_down + BN + ReLU -> bufA [b,c,(h,w)]
    gemm_mfma<128, 64><<<NB * 49, 256, 0, stream>>>(x, cdw, bn1, nullptr, bufA, 0, 1);
    // 2. transpose -> bufB [b,c,(w,h)]
    transpose_hw<<<NB * CD, 256, 0, stream>>>(bufA, bufB);
    // 3. qkv GEMM (H) -> qpack, kvpack
    qkv_gemm_mfma<<<NB * 49, 256, 0, stream>>>(bufB, hqkv, hbnqkv, hbnsim, qpack, kvpack);
    // 4. attn H: p=w, i=h -> bufA [b,c,w,h]
    attn_core<<<NB * S, 512, 0, stream>>>(qpack, kvpack, hbnsim, hbnout, hrel, bufA);
    // 5. transpose -> bufB [b,c,(h,w)]
    transpose_hw<<<NB * CD, 256, 0, stream>>>(bufA, bufB);
    // 6. qkv GEMM (W) -> qpack, kvpack
    qkv_gemm_mfma<<<NB * 49, 256, 0, stream>>>(bufB, wqkv, wbnqkv, wbnsim, qpack, kvpack);
    // 7. attn W: p=h, i=w -> bufA [b,c,h,w]
    attn_core<<<NB * S, 512, 0, stream>>>(qpack, kvpack, wbnsim, wbnout, wrel, bufA);
    // 8. ReLU-in + conv_up + BN + resid + ReLU -> d_out
    gemm_mfma<64, 128><<<NB * 49, 256, 0, stream>>>(bufA, cuw, bn2, x, (float*)d_out, 1, 1);
}